// Round 1
// baseline (1154.316 us; speedup 1.0000x reference)
//
#include <hip/hip_runtime.h>

// WRGCN layer: out = sum_r scatter_add(tgt, (X[src] @ W_r) * ew) + presence*bias + X @ W_self
// N=200000, D_IN=D_OUT=256, R=8, E=150000. All fp32 in/out; bf16 MFMA internally.

#define N_ENT 200000
#define D 256
#define R_REL 8
#define E_EDGE 150000

typedef __bf16 bf16x8 __attribute__((ext_vector_type(8)));
typedef unsigned short u16x8 __attribute__((ext_vector_type(8)));
typedef float f32x4 __attribute__((ext_vector_type(4)));

__device__ __forceinline__ unsigned short f2bf(float f) {
  unsigned int u = __builtin_bit_cast(unsigned int, f);
  u += 0x7FFFu + ((u >> 16) & 1u);   // RNE (inputs finite)
  return (unsigned short)(u >> 16);
}

__device__ __forceinline__ f32x4 mfma16(u16x8 a, u16x8 b, f32x4 c) {
  return __builtin_amdgcn_mfma_f32_16x16x32_bf16(
      __builtin_bit_cast(bf16x8, a), __builtin_bit_cast(bf16x8, b), c, 0, 0, 0);
}

// ---- X (f32) -> Xh (bf16), 8 elems/thread, exact grid ----
__global__ __launch_bounds__(256) void k_cvt_x(const float* __restrict__ x,
                                               unsigned short* __restrict__ xh) {
  int i = blockIdx.x * 256 + threadIdx.x;
  const float4* xv = (const float4*)x;
  float4 a = xv[2 * i], b = xv[2 * i + 1];
  uint4 o;
  o.x = (unsigned)f2bf(a.x) | ((unsigned)f2bf(a.y) << 16);
  o.y = (unsigned)f2bf(a.z) | ((unsigned)f2bf(a.w) << 16);
  o.z = (unsigned)f2bf(b.x) | ((unsigned)f2bf(b.y) << 16);
  o.w = (unsigned)f2bf(b.z) | ((unsigned)f2bf(b.w) << 16);
  ((uint4*)xh)[i] = o;
}

// ---- Weights -> bf16 pre-swizzled into MFMA B-fragment order ----
// Wf[rel][kb][nb][lane][j]  (rel 0..7 = relations, rel 8 = self_weight)
// element = W[k = kb*32 + (lane>>4)*8 + j][n = nb*16 + (lane&15)]
__global__ __launch_bounds__(256) void k_cvt_w(const float* __restrict__ relw,
                                               const float* __restrict__ selfw,
                                               unsigned short* __restrict__ wf) {
  int t = blockIdx.x * 256 + threadIdx.x;   // 9*8*16*64 = 73728 total
  int rel = t >> 13;
  int rem = t & 8191;
  int kb = rem >> 10;
  int nb = (rem >> 6) & 15;
  int lane = rem & 63;
  const float* W = (rel < R_REL) ? (relw + rel * D * D) : selfw;
  int k0 = kb * 32 + (lane >> 4) * 8;
  int n = nb * 16 + (lane & 15);
  unsigned int o[4];
#pragma unroll
  for (int jj = 0; jj < 4; ++jj) {
    unsigned lo = f2bf(W[(k0 + 2 * jj) * D + n]);
    unsigned hi = f2bf(W[(k0 + 2 * jj + 1) * D + n]);
    o[jj] = lo | (hi << 16);
  }
  uint4 v = make_uint4(o[0], o[1], o[2], o[3]);
  ((uint4*)wf)[t] = v;
}

// ---- Self GEMM: out = X @ W_self (initializes out) ----
// Block: 64 rows x 256 cols, 4 waves; A in LDS with XOR swizzle (G4).
__global__ __launch_bounds__(256) void k_self(const unsigned short* __restrict__ xh,
                                              const unsigned short* __restrict__ wfb,
                                              float* __restrict__ out) {
  __shared__ unsigned char As[64 * 512];
  int row0 = blockIdx.x * 64;
  int tid = threadIdx.x;
#pragma unroll
  for (int it = 0; it < 8; ++it) {
    int c = tid + it * 256;             // 2048 chunks of 16B
    int row = c >> 5, col16 = c & 31;
    uint4 v = *(const uint4*)(xh + (row0 + row) * 256 + col16 * 8);
    int wb = (row * 512 + col16 * 16) ^ ((row & 7) << 4);
    *(uint4*)(As + wb) = v;
  }
  __syncthreads();
  int w = tid >> 6, lane = tid & 63;
  int lm = lane & 15, lk = lane >> 4;
  f32x4 acc[4][4] = {};
#pragma unroll
  for (int kb = 0; kb < 8; ++kb) {
    u16x8 a[4], b[4];
#pragma unroll
    for (int mi = 0; mi < 4; ++mi) {
      int row = mi * 16 + lm;
      int byt = (row * 512 + kb * 64 + lk * 16) ^ ((row & 7) << 4);
      a[mi] = *(const u16x8*)(As + byt);
    }
#pragma unroll
    for (int ni = 0; ni < 4; ++ni) {
      int nb = w * 4 + ni;
      b[ni] = *(const u16x8*)(wfb + ((kb * 16 + nb) * 64 + lane) * 8);
    }
#pragma unroll
    for (int mi = 0; mi < 4; ++mi)
#pragma unroll
      for (int ni = 0; ni < 4; ++ni)
        acc[mi][ni] = mfma16(a[mi], b[ni], acc[mi][ni]);
  }
#pragma unroll
  for (int mi = 0; mi < 4; ++mi)
#pragma unroll
    for (int ni = 0; ni < 4; ++ni) {
      int col = w * 64 + ni * 16 + lm;
#pragma unroll
      for (int j = 0; j < 4; ++j) {
        int row = row0 + mi * 16 + lk * 4 + j;
        out[row * 256 + col] = acc[mi][ni][j];
      }
    }
}

// ---- Edge kernel: gather X[src] -> GEMM vs W_r -> *ew -> atomicAdd out[tgt] ----
__global__ __launch_bounds__(256) void k_edge(const unsigned short* __restrict__ xh,
                                              const unsigned short* __restrict__ wf,
                                              const int* __restrict__ edge_index,
                                              const float* __restrict__ ew,
                                              float* __restrict__ out) {
  __shared__ unsigned char As[64 * 512];
  __shared__ int src_s[64];
  __shared__ int tgt_s[64];
  __shared__ float ew_s[64];
  int rel = blockIdx.y;
  int e0 = blockIdx.x * 64;
  int tid = threadIdx.x;
  if (tid < 64) {
    int e = e0 + tid;
    bool valid = e < E_EDGE;
    const int* ei = edge_index + rel * 2 * E_EDGE;
    src_s[tid] = valid ? ei[e] : 0;
    tgt_s[tid] = valid ? ei[E_EDGE + e] : 0;
    ew_s[tid] = valid ? ew[rel * E_EDGE + e] : 0.0f;
  }
  __syncthreads();
#pragma unroll
  for (int it = 0; it < 8; ++it) {
    int c = tid + it * 256;
    int row = c >> 5, col16 = c & 31;
    uint4 v = *(const uint4*)(xh + src_s[row] * 256 + col16 * 8);
    int wb = (row * 512 + col16 * 16) ^ ((row & 7) << 4);
    *(uint4*)(As + wb) = v;
  }
  __syncthreads();
  int w = tid >> 6, lane = tid & 63;
  int lm = lane & 15, lk = lane >> 4;
  const unsigned short* wfb = wf + rel * 65536;
  f32x4 acc[4][4] = {};
#pragma unroll
  for (int kb = 0; kb < 8; ++kb) {
    u16x8 a[4], b[4];
#pragma unroll
    for (int mi = 0; mi < 4; ++mi) {
      int row = mi * 16 + lm;
      int byt = (row * 512 + kb * 64 + lk * 16) ^ ((row & 7) << 4);
      a[mi] = *(const u16x8*)(As + byt);
    }
#pragma unroll
    for (int ni = 0; ni < 4; ++ni) {
      int nb = w * 4 + ni;
      b[ni] = *(const u16x8*)(wfb + ((kb * 16 + nb) * 64 + lane) * 8);
    }
#pragma unroll
    for (int mi = 0; mi < 4; ++mi)
#pragma unroll
      for (int ni = 0; ni < 4; ++ni)
        acc[mi][ni] = mfma16(a[mi], b[ni], acc[mi][ni]);
  }
#pragma unroll
  for (int mi = 0; mi < 4; ++mi)
#pragma unroll
    for (int ni = 0; ni < 4; ++ni) {
      int col = w * 64 + ni * 16 + lm;
#pragma unroll
      for (int j = 0; j < 4; ++j) {
        int lrow = mi * 16 + lk * 4 + j;
        float val = acc[mi][ni][j] * ew_s[lrow];
        atomicAdd(&out[tgt_s[lrow] * 256 + col], val);
      }
    }
}

// ---- presence flags: flags[tgt*8 + r] = 1 ----
__global__ void k_flags(const int* __restrict__ ei, unsigned char* __restrict__ flags) {
  int r = blockIdx.y;
  int e = blockIdx.x * 256 + threadIdx.x;
  if (e >= E_EDGE) return;
  int tgt = ei[(r * 2 + 1) * E_EDGE + e];
  flags[tgt * 8 + r] = 1;
}

// ---- bias: out[n][col] += sum_r present(r,n) * b[r][col]; skip RMW when sum==0 ----
__global__ __launch_bounds__(256) void k_bias(const unsigned long long* __restrict__ flags8,
                                              const float* __restrict__ bias,
                                              float* __restrict__ out) {
  int col = threadIdx.x;
  int n0 = blockIdx.x * 8;
  float bcol[8];
#pragma unroll
  for (int r = 0; r < 8; ++r) bcol[r] = bias[r * 256 + col];
#pragma unroll
  for (int k = 0; k < 8; ++k) {
    int n = n0 + k;
    unsigned long long f = flags8[n];
    if (!f) continue;
    float s = 0.f;
#pragma unroll
    for (int r = 0; r < 8; ++r)
      if ((f >> (8 * r)) & 0xffULL) s += bcol[r];
    if (s != 0.f) out[n * 256 + col] += s;
  }
}

extern "C" void kernel_launch(void* const* d_in, const int* in_sizes, int n_in,
                              void* d_out, int out_size, void* d_ws, size_t ws_size,
                              hipStream_t stream) {
  const float* x = (const float*)d_in[0];
  const float* relw = (const float*)d_in[1];
  const float* selfw = (const float*)d_in[2];
  const float* bias = (const float*)d_in[3];
  const int* ei = (const int*)d_in[4];
  const float* ew = (const float*)d_in[5];
  float* out = (float*)d_out;

  char* ws = (char*)d_ws;
  unsigned short* xh = (unsigned short*)ws;                         // 102,400,000 B
  unsigned short* wf = (unsigned short*)(ws + 102400000);           // 1,179,648 B
  unsigned char* flags = (unsigned char*)(ws + 102400000 + 1179648); // 1,600,000 B

  hipMemsetAsync(flags, 0, (size_t)N_ENT * 8, stream);
  k_cvt_x<<<(N_ENT * D) / 2048, 256, 0, stream>>>(x, xh);
  k_cvt_w<<<(9 * 8 * 16 * 64) / 256, 256, 0, stream>>>(relw, selfw, wf);
  k_self<<<N_ENT / 64, 256, 0, stream>>>(xh, wf + 8 * 65536, out);
  k_edge<<<dim3((E_EDGE + 63) / 64, R_REL), 256, 0, stream>>>(xh, wf, ei, ew, out);
  k_flags<<<dim3((E_EDGE + 255) / 256, R_REL), 256, 0, stream>>>(ei, flags);
  k_bias<<<N_ENT / 8, 256, 0, stream>>>((const unsigned long long*)flags, bias, out);
}

// Round 2
// 1071.707 us; speedup vs baseline: 1.0771x; 1.0771x over previous
//
#include <hip/hip_runtime.h>

// WRGCN: out[t] = sum_r (sum_{e:tgt=t,rel=r} ew_e * X[src_e]) @ W_r  + X[t] @ W_self + P @ bias
// Counting-sort edges by key=tgt*8+r, then fused aggregate+GEMM, no atomics on out.

#define N_ENT 200000
#define D 256
#define R_REL 8
#define E_EDGE 150000
#define TOT_E (R_REL * E_EDGE)        // 1,200,000
#define MKEY (N_ENT * R_REL)          // 1,600,000
#define SCAN_B 1024
#define NBLK_SCAN ((MKEY + SCAN_B - 1) / SCAN_B)   // 1563

typedef __bf16 bf16x8 __attribute__((ext_vector_type(8)));
typedef unsigned short u16x8 __attribute__((ext_vector_type(8)));
typedef float f32x4 __attribute__((ext_vector_type(4)));

__device__ __forceinline__ unsigned short f2bf(float f) {
  unsigned int u = __builtin_bit_cast(unsigned int, f);
  u += 0x7FFFu + ((u >> 16) & 1u);   // RNE (inputs finite)
  return (unsigned short)(u >> 16);
}
__device__ __forceinline__ float bf2f(unsigned short u) {
  return __builtin_bit_cast(float, ((unsigned)u) << 16);
}
__device__ __forceinline__ f32x4 mfma16(u16x8 a, u16x8 b, f32x4 c) {
  return __builtin_amdgcn_mfma_f32_16x16x32_bf16(
      __builtin_bit_cast(bf16x8, a), __builtin_bit_cast(bf16x8, b), c, 0, 0, 0);
}

// ---- X (f32) -> Xh (bf16) ----
__global__ __launch_bounds__(256) void k_cvt_x(const float* __restrict__ x,
                                               unsigned short* __restrict__ xh) {
  int i = blockIdx.x * 256 + threadIdx.x;
  const float4* xv = (const float4*)x;
  float4 a = xv[2 * i], b = xv[2 * i + 1];
  uint4 o;
  o.x = (unsigned)f2bf(a.x) | ((unsigned)f2bf(a.y) << 16);
  o.y = (unsigned)f2bf(a.z) | ((unsigned)f2bf(a.w) << 16);
  o.z = (unsigned)f2bf(b.x) | ((unsigned)f2bf(b.y) << 16);
  o.w = (unsigned)f2bf(b.z) | ((unsigned)f2bf(b.w) << 16);
  ((uint4*)xh)[i] = o;
}

// ---- Weights -> bf16 MFMA B-fragment order. tile rel 0..7 = W_r, 8 = self ----
__global__ __launch_bounds__(256) void k_cvt_w(const float* __restrict__ relw,
                                               const float* __restrict__ selfw,
                                               unsigned short* __restrict__ wf) {
  int t = blockIdx.x * 256 + threadIdx.x;   // 9*8*16*64 = 73728
  int rel = t >> 13;
  int rem = t & 8191;
  int kb = rem >> 10;
  int nb = (rem >> 6) & 15;
  int lane = rem & 63;
  const float* W = (rel < R_REL) ? (relw + rel * D * D) : selfw;
  int k0 = kb * 32 + (lane >> 4) * 8;
  int n = nb * 16 + (lane & 15);
  unsigned int o[4];
#pragma unroll
  for (int jj = 0; jj < 4; ++jj) {
    unsigned lo = f2bf(W[(k0 + 2 * jj) * D + n]);
    unsigned hi = f2bf(W[(k0 + 2 * jj + 1) * D + n]);
    o[jj] = lo | (hi << 16);
  }
  ((uint4*)wf)[t] = make_uint4(o[0], o[1], o[2], o[3]);
}

// ---- bias -> B-fragment tile for K=8 presence MFMA: [nb][lane][8] ----
__global__ __launch_bounds__(256) void k_cvt_bias(const float* __restrict__ bias,
                                                  unsigned short* __restrict__ bb) {
  int t = blockIdx.x * 256 + threadIdx.x;   // 16*64 = 1024
  int nb = t >> 6, lane = t & 63;
  int lk = lane >> 4, n = nb * 16 + (lane & 15);
  unsigned int o[4];
#pragma unroll
  for (int jj = 0; jj < 4; ++jj) {
    unsigned lo = 0, hi = 0;
    if (lk == 0) {                       // k = lk*8 + j; only k<8 nonzero
      lo = f2bf(bias[(2 * jj) * D + n]);
      hi = f2bf(bias[(2 * jj + 1) * D + n]);
    }
    o[jj] = lo | (hi << 16);
  }
  ((uint4*)bb)[t] = make_uint4(o[0], o[1], o[2], o[3]);
}

// ---- histogram over key = tgt*8 + r ----
__global__ __launch_bounds__(256) void k_hist(const int* __restrict__ ei,
                                              unsigned* __restrict__ counts) {
  int t = blockIdx.x * 256 + threadIdx.x;
  if (t >= TOT_E) return;
  int r = t / E_EDGE, e = t - r * E_EDGE;
  int tgt = ei[(r * 2 + 1) * E_EDGE + e];
  atomicAdd(&counts[tgt * 8 + r], 1u);
}

// ---- exclusive scan (3 kernels) ----
__global__ __launch_bounds__(256) void k_scan1(const unsigned* __restrict__ cnt,
                                               unsigned* __restrict__ off,
                                               unsigned* __restrict__ aux) {
  __shared__ unsigned sc[256];
  int tid = threadIdx.x;
  int base = blockIdx.x * SCAN_B + tid * 4;
  unsigned v[4];
#pragma unroll
  for (int j = 0; j < 4; ++j) v[j] = (base + j < MKEY) ? cnt[base + j] : 0u;
  unsigned s = v[0] + v[1] + v[2] + v[3];
  sc[tid] = s;
  __syncthreads();
  for (int o = 1; o < 256; o <<= 1) {
    unsigned t = (tid >= o) ? sc[tid - o] : 0u;
    __syncthreads();
    sc[tid] += t;
    __syncthreads();
  }
  unsigned excl = sc[tid] - s;
  if (tid == 255) aux[blockIdx.x] = sc[255];
#pragma unroll
  for (int j = 0; j < 4; ++j) {
    if (base + j < MKEY) off[base + j] = excl;
    excl += v[j];
  }
}

__global__ __launch_bounds__(256) void k_scan2(unsigned* __restrict__ aux) {
  __shared__ unsigned sc[256];
  int tid = threadIdx.x;
  int base = tid * 7;
  unsigned v[7];
#pragma unroll
  for (int j = 0; j < 7; ++j) v[j] = (base + j < NBLK_SCAN) ? aux[base + j] : 0u;
  unsigned s = 0;
#pragma unroll
  for (int j = 0; j < 7; ++j) s += v[j];
  sc[tid] = s;
  __syncthreads();
  for (int o = 1; o < 256; o <<= 1) {
    unsigned t = (tid >= o) ? sc[tid - o] : 0u;
    __syncthreads();
    sc[tid] += t;
    __syncthreads();
  }
  unsigned excl = sc[tid] - s;
#pragma unroll
  for (int j = 0; j < 7; ++j) {
    if (base + j < NBLK_SCAN) aux[base + j] = excl;
    excl += v[j];
  }
}

__global__ __launch_bounds__(256) void k_scan3(unsigned* __restrict__ off,
                                               const unsigned* __restrict__ aux) {
  unsigned add = aux[blockIdx.x];
  int base = blockIdx.x * SCAN_B + threadIdx.x * 4;
  if (base + 3 < MKEY) {
    uint4* p = (uint4*)(off + base);
    uint4 x = *p;
    x.x += add; x.y += add; x.z += add; x.w += add;
    *p = x;
  } else {
    for (int j = 0; j < 4; ++j)
      if (base + j < MKEY) off[base + j] += add;
  }
}

// ---- scatter (src, ew) into sorted order; offsets become segment ENDs ----
__global__ __launch_bounds__(256) void k_scatter(const int* __restrict__ ei,
                                                 const float* __restrict__ ew,
                                                 unsigned* __restrict__ off,
                                                 int* __restrict__ ssrc,
                                                 float* __restrict__ sew) {
  int t = blockIdx.x * 256 + threadIdx.x;
  if (t >= TOT_E) return;
  int r = t / E_EDGE, e = t - r * E_EDGE;
  int tgt = ei[(r * 2 + 1) * E_EDGE + e];
  int src = ei[(r * 2) * E_EDGE + e];
  float w = ew[t];                        // ew is [R][E], t = r*E+e
  unsigned pos = atomicAdd(&off[tgt * 8 + r], 1u);
  ssrc[pos] = src;
  sew[pos] = w;
}

// ---- fused: per 64 target rows — self GEMM + 8 x (aggregate -> GEMM) + bias MFMA -> store ----
__global__ __launch_bounds__(256) void k_main(const unsigned short* __restrict__ xh,
                                              const unsigned short* __restrict__ wf,
                                              const unsigned short* __restrict__ bbf,
                                              const unsigned* __restrict__ counts,
                                              const unsigned* __restrict__ off_end,
                                              const int* __restrict__ ssrc,
                                              const float* __restrict__ sew,
                                              float* __restrict__ out) {
  __shared__ unsigned char As[64 * 512];
  int n0 = blockIdx.x * 64;
  int tid = threadIdx.x;
  int w = tid >> 6, lane = tid & 63;
  int lm = lane & 15, lk = lane >> 4;
  f32x4 acc[4][4] = {};

  for (int p = 0; p < 9; ++p) {
    if (p == 0) {
      // stage X rows n0..n0+63 (self term)
#pragma unroll
      for (int it = 0; it < 8; ++it) {
        int c = tid + it * 256;
        int row = c >> 5, col16 = c & 31;
        uint4 v = *(const uint4*)(xh + (n0 + row) * 256 + col16 * 8);
        int wb = (row * 512 + col16 * 16) ^ ((row & 7) << 4);
        *(uint4*)(As + wb) = v;
      }
    } else {
      int r = p - 1;
      // wave w aggregates rows w*16..w*16+15 for relation r
      for (int g16 = 0; g16 < 16; ++g16) {
        int g = w * 16 + g16;
        int key = (n0 + g) * 8 + r;
        unsigned end = off_end[key];
        unsigned cnt = counts[key];
        float a0 = 0.f, a1 = 0.f, a2 = 0.f, a3 = 0.f;
        unsigned i = end - cnt;
        if (cnt) {
          int s = ssrc[i];
          float wt = sew[i];
          for (;;) {
            ushort4 xv = *(const ushort4*)(xh + (unsigned)s * 256u + lane * 4);
            ++i;
            int sn = 0; float wn = 0.f;
            if (i < end) { sn = ssrc[i]; wn = sew[i]; }   // prefetch next edge
            a0 += wt * bf2f(xv.x);
            a1 += wt * bf2f(xv.y);
            a2 += wt * bf2f(xv.z);
            a3 += wt * bf2f(xv.w);
            if (i >= end) break;
            s = sn; wt = wn;
          }
        }
        unsigned lo = (unsigned)f2bf(a0) | ((unsigned)f2bf(a1) << 16);
        unsigned hi = (unsigned)f2bf(a2) | ((unsigned)f2bf(a3) << 16);
        int wb = ((g * 512 + (lane >> 1) * 16) ^ ((g & 7) << 4)) + (lane & 1) * 8;
        *(uint2*)(As + wb) = make_uint2(lo, hi);
      }
    }
    __syncthreads();

    const unsigned short* wfb = wf + ((p == 0) ? 8 : (p - 1)) * 65536;
#pragma unroll
    for (int kb = 0; kb < 8; ++kb) {
      u16x8 a[4], b[4];
#pragma unroll
      for (int mi = 0; mi < 4; ++mi) {
        int row = mi * 16 + lm;
        int byt = (row * 512 + kb * 64 + lk * 16) ^ ((row & 7) << 4);
        a[mi] = *(const u16x8*)(As + byt);
      }
#pragma unroll
      for (int ni = 0; ni < 4; ++ni) {
        int nb = w * 4 + ni;
        b[ni] = *(const u16x8*)(wfb + ((kb * 16 + nb) * 64 + lane) * 8);
      }
#pragma unroll
      for (int mi = 0; mi < 4; ++mi)
#pragma unroll
        for (int ni = 0; ni < 4; ++ni)
          acc[mi][ni] = mfma16(a[mi], b[ni], acc[mi][ni]);
    }
    __syncthreads();
  }

  // ---- bias via presence MFMA: P[64x8] @ bias[8x256] ----
  {
    u16x8 bb[4];
#pragma unroll
    for (int ni = 0; ni < 4; ++ni)
      bb[ni] = *(const u16x8*)(bbf + ((w * 4 + ni) * 64 + lane) * 8);
#pragma unroll
    for (int mi = 0; mi < 4; ++mi) {
      u16x8 pa = {};
      if (lk == 0) {
        int base = (n0 + mi * 16 + lm) * 8;
        uint4 c0 = *(const uint4*)(counts + base);
        uint4 c1 = *(const uint4*)(counts + base + 4);
        pa[0] = c0.x ? 0x3F80 : 0; pa[1] = c0.y ? 0x3F80 : 0;
        pa[2] = c0.z ? 0x3F80 : 0; pa[3] = c0.w ? 0x3F80 : 0;
        pa[4] = c1.x ? 0x3F80 : 0; pa[5] = c1.y ? 0x3F80 : 0;
        pa[6] = c1.z ? 0x3F80 : 0; pa[7] = c1.w ? 0x3F80 : 0;
      }
#pragma unroll
      for (int ni = 0; ni < 4; ++ni)
        acc[mi][ni] = mfma16(pa, bb[ni], acc[mi][ni]);
    }
  }

  // ---- epilogue: single coalesced-ish store per element ----
#pragma unroll
  for (int mi = 0; mi < 4; ++mi)
#pragma unroll
    for (int ni = 0; ni < 4; ++ni) {
      int col = w * 64 + ni * 16 + lm;
#pragma unroll
      for (int j = 0; j < 4; ++j) {
        int row = n0 + mi * 16 + lk * 4 + j;
        out[row * 256 + col] = acc[mi][ni][j];
      }
    }
}

extern "C" void kernel_launch(void* const* d_in, const int* in_sizes, int n_in,
                              void* d_out, int out_size, void* d_ws, size_t ws_size,
                              hipStream_t stream) {
  const float* x = (const float*)d_in[0];
  const float* relw = (const float*)d_in[1];
  const float* selfw = (const float*)d_in[2];
  const float* bias = (const float*)d_in[3];
  const int* ei = (const int*)d_in[4];
  const float* ew = (const float*)d_in[5];
  float* out = (float*)d_out;

  char* ws = (char*)d_ws;
  unsigned short* xh = (unsigned short*)ws;                          // 102,400,000
  unsigned short* wf = (unsigned short*)(ws + 102400000);            //   1,179,648
  unsigned short* bbf = (unsigned short*)(ws + 103579648);           //      16,384
  unsigned* counts = (unsigned*)(ws + 103596032);                    //   6,400,000
  unsigned* offs = (unsigned*)(ws + 109996032);                      //   6,400,000
  unsigned* aux = (unsigned*)(ws + 116396032);                       //       8,192
  int* ssrc = (int*)(ws + 116404224);                                //   4,800,000
  float* sew = (float*)(ws + 121204224);                             //   4,800,000  -> 126,004,224 total

  hipMemsetAsync(counts, 0, (size_t)MKEY * 4, stream);
  k_cvt_x<<<(N_ENT * D) / 2048, 256, 0, stream>>>(x, xh);
  k_cvt_w<<<288, 256, 0, stream>>>(relw, selfw, wf);
  k_cvt_bias<<<4, 256, 0, stream>>>(bias, bbf);
  k_hist<<<(TOT_E + 255) / 256, 256, 0, stream>>>(ei, counts);
  k_scan1<<<NBLK_SCAN, 256, 0, stream>>>(counts, offs, aux);
  k_scan2<<<1, 256, 0, stream>>>(aux);
  k_scan3<<<NBLK_SCAN, 256, 0, stream>>>(offs, aux);
  k_scatter<<<(TOT_E + 255) / 256, 256, 0, stream>>>(ei, ew, offs, ssrc, sew);
  k_main<<<N_ENT / 64, 256, 0, stream>>>(xh, wf, bbf, counts, offs, ssrc, sew, out);
}